// Round 3
// baseline (504.475 us; speedup 1.0000x reference)
//
#include <hip/hip_runtime.h>

#define DIM 4096
#define LPT 16      // float4 loads per lane
#define EPL 64      // elements per lane
#define NBIN 512

// Order-preserving float<->uint key. Larger float <=> larger key.
__device__ __forceinline__ unsigned int f2key(float f) {
  unsigned int u = __float_as_uint(f);
  unsigned int m = (unsigned int)((int)u >> 31) | 0x80000000u;
  return u ^ m;
}
// Inverse. Top bit set => originally positive => XOR 0x80000000.
//          Top bit clear => originally negative => XOR 0xFFFFFFFF.
__device__ __forceinline__ float key2f(unsigned int k) {
  unsigned int m = ((int)k < 0) ? 0x80000000u : 0xFFFFFFFFu;
  return __uint_as_float(k ^ m);
}
// Monotone value-spread bin. MUST be the single definition used everywhere
// (histogram AND survivor predicate) so counts stay exactly consistent.
__device__ __forceinline__ int binof(float xf) {
  int b = (int)fmaf(xf, 64.0f, 256.0f);
  return min(NBIN - 1, max(0, b));
}

// One wave (64 threads) per row of 4096. Exact top-k threshold via:
// coarse monotone 512-bin histogram -> survivor mask (bin == selbin,
// recomputed bit-consistently) -> (rare) mask bisection -> compact <=64
// survivors one/lane -> 32-step ballot bit-radix. Exact, index-stable ties.
__global__ __launch_bounds__(64) void topk_mask_kernel(
    const float* __restrict__ x, float* __restrict__ out, int k) {
  const int row  = blockIdx.x;
  const int lane = threadIdx.x;   // 0..63, one wave
  const long base = (long)row * DIM;
  const float4* xv = (const float4*)(x + base);

  __shared__ __align__(16) unsigned int hist[NBIN];
  __shared__ unsigned int cbuf[64];

  // ---- zero histogram (8 bins/lane, vectorized) ----
  uint4 z = make_uint4(0, 0, 0, 0);
  ((uint4*)hist)[lane * 2 + 0] = z;
  ((uint4*)hist)[lane * 2 + 1] = z;
  __syncthreads();

  // ---- load 64 elems/lane (coalesced float4), histogram + key convert ----
  unsigned int key[EPL];
#pragma unroll
  for (int j = 0; j < LPT; ++j) {
    float4 v = xv[j * 64 + lane];
    const float* f = (const float*)&v;
#pragma unroll
    for (int c = 0; c < 4; ++c) {
      atomicAdd(&hist[binof(f[c])], 1u);
      key[j * 4 + c] = f2key(f[c]);
    }
  }
  __syncthreads();

  // ---- find the bin containing rank k (from the top) ----
  // lane owns bins [8*lane, 8*lane+8); higher bin => larger values.
  uint4 h0 = ((const uint4*)hist)[lane * 2 + 0];
  uint4 h1 = ((const uint4*)hist)[lane * 2 + 1];
  unsigned int c8[8] = {h0.x, h0.y, h0.z, h0.w, h1.x, h1.y, h1.z, h1.w};
  unsigned int lt = 0;
#pragma unroll
  for (int i = 0; i < 8; ++i) lt += c8[i];
  unsigned int s = lt;    // inclusive suffix-scan over lanes
#pragma unroll
  for (int off = 1; off < 64; off <<= 1) {
    unsigned int vv = __shfl_down(s, off);
    if (lane + off < 64) s += vv;
  }
  unsigned int above = s - lt;   // elems in bins owned by higher lanes
  int selslot = -1;
  unsigned int selA = 0, selC = 0, acc = above;
#pragma unroll
  for (int i = 7; i >= 0; --i) {   // descending bin within lane
    if (selslot < 0 && acc < (unsigned)k && (unsigned)k <= acc + c8[i]) {
      selslot = i; selA = acc; selC = c8[i];
    }
    acc += c8[i];
  }
  unsigned long long bal = __ballot(selslot >= 0);  // exactly one lane set
  int sellane = __ffsll(bal) - 1;
  int selbin  = __shfl(selslot, sellane) + 8 * sellane;
  unsigned int A     = (unsigned int)__shfl((int)selA, sellane);
  unsigned int m     = (unsigned int)__shfl((int)selC, sellane);
  unsigned int k_rem = (unsigned)k - A;   // rank within selected bin

  // ---- survivor mask: same bin function, bit-exact vs histogram ----
  unsigned long long cur = 0;
#pragma unroll
  for (int e = 0; e < EPL; ++e) {
    if (binof(key2f(key[e])) == selbin) cur |= 1ull << e;
  }

  // ---- rare: narrow candidate set by key bisection until m <= 64 ----
  bool allequal = false;
  unsigned long long lo = 0, hi = 1ull << 32;
  unsigned int t, rr, E;
  while (m > 64) {
    if (hi - lo == 1ull) { allequal = true; break; }  // all remaining equal
    unsigned int mid = (unsigned int)((lo + hi) >> 1);
    unsigned long long up = 0;
#pragma unroll
    for (int e = 0; e < EPL; ++e) {
      if (((cur >> e) & 1ull) && key[e] >= mid) up |= 1ull << e;
    }
    unsigned int cnt = __popcll(up);
#pragma unroll
    for (int off = 1; off < 64; off <<= 1) cnt += __shfl_xor(cnt, off);
    if (k_rem <= cnt) { cur = up; m = cnt; lo = mid; }
    else { k_rem -= cnt; cur &= ~up; m -= cnt; hi = mid; }
  }

  if (allequal) {
    t = (unsigned int)lo; rr = k_rem; E = m;
  } else {
    // ---- compact candidates (<=64) to one per lane ----
    unsigned int myc = __popcll(cur);
    unsigned int p = myc;
#pragma unroll
    for (int off = 1; off < 64; off <<= 1) {
      unsigned int vv = __shfl_up(p, off);
      if (lane >= off) p += vv;
    }
    unsigned int w = p - myc;   // exclusive prefix
#pragma unroll
    for (int e = 0; e < EPL; ++e) {
      if ((cur >> e) & 1ull) cbuf[w++] = key[e];
    }
    __syncthreads();
    unsigned int ck = (lane < (int)m) ? cbuf[lane] : 0u;

    // ---- exact k_rem-th largest among m values: ballot bit-radix ----
    unsigned long long cand = __ballot(lane < (int)m);
    t = 0; rr = k_rem;
#pragma unroll
    for (int bit = 31; bit >= 0; --bit) {
      unsigned long long ones = __ballot((ck >> bit) & 1u) & cand;
      unsigned int c = __popcll(ones);
      if (rr <= c) { cand = ones; t |= 1u << bit; }
      else { rr -= c; cand &= ~ones; }
    }
    E = __popcll(cand);   // total elements equal to t (all equals survive)
  }

  // ---- tie handling: keep first rr equals in ascending element index ----
  const bool keepall = (rr == E);
  unsigned long long keep_eq = 0;
  if (!keepall) {   // rare; wave-uniform branch
    unsigned long long eqm = 0;
#pragma unroll
    for (int e = 0; e < EPL; ++e)
      if (key[e] == t) eqm |= 1ull << e;
    unsigned int run = 0;
    for (int j = 0; j < LPT; ++j) {  // ascending global idx: j major, lane, c
      unsigned int cj = __popc((unsigned int)((eqm >> (4 * j)) & 0xFull));
      unsigned int pj = cj;
#pragma unroll
      for (int off = 1; off < 64; off <<= 1) {
        unsigned int vv = __shfl_up(pj, off);
        if (lane >= off) pj += vv;
      }
      unsigned int basej = run + pj - cj;
#pragma unroll
      for (int c = 0; c < 4; ++c) {
        int e2 = 4 * j + c;
        if ((eqm >> e2) & 1ull) {
          if (basej < rr) keep_eq |= 1ull << e2;
          basej++;
        }
      }
      run += (unsigned int)__shfl((int)pj, 63);
    }
  }

  // ---- write: x where kept, 0 elsewhere (coalesced float4) ----
  float4* ov = (float4*)(out + base);
#pragma unroll
  for (int j = 0; j < LPT; ++j) {
    float4 o;
    float* op = (float*)&o;
#pragma unroll
    for (int c = 0; c < 4; ++c) {
      int e = 4 * j + c;
      unsigned int kk = key[e];
      bool keep = keepall ? (kk >= t)
                          : ((kk > t) || ((keep_eq >> e) & 1ull));
      op[c] = keep ? key2f(kk) : 0.0f;
    }
    ov[j * 64 + lane] = o;
  }
}

extern "C" void kernel_launch(void* const* d_in, const int* in_sizes, int n_in,
                              void* d_out, int out_size, void* d_ws, size_t ws_size,
                              hipStream_t stream) {
  const float* x = (const float*)d_in[0];
  float* out = (float*)d_out;
  const int rows = in_sizes[0] / DIM;   // 4*4096 = 16384
  const int k = DIM / 2;                // TOPK==0 -> k = D/2
  topk_mask_kernel<<<rows, 64, 0, stream>>>(x, out, k);
}